// Round 2
// baseline (156.788 us; speedup 1.0000x reference)
//
#include <hip/hip_runtime.h>
#include <hip/hip_bf16.h>

// DenseGridNet: bilinear gather + MLP(5->64->64->3) + sigmoid, bf16 MFMA.
// R2: slot-permuted B columns so epilogues are cvt_pk + ds_write_b64;
//     bias via acc-init; XOR-swizzled 64-wide Lh (36KB LDS -> 4 blocks/CU).

typedef __attribute__((ext_vector_type(8))) short bf16x8;
typedef __attribute__((ext_vector_type(4))) float f32x4;
typedef __attribute__((ext_vector_type(2))) unsigned int u32x2;
typedef __attribute__((ext_vector_type(4))) unsigned int u32x4;

#define HID 64

static __device__ __forceinline__ unsigned short f2bf(float f) {
    __hip_bfloat16 h = __float2bfloat16(f);
    return __builtin_bit_cast(unsigned short, h);
}
// dst.lo = bf16(a), dst.hi = bf16(b)  (HW RNE, 1 instr for 2 converts)
static __device__ __forceinline__ unsigned cvt_pk_bf16(float a, float b) {
    unsigned r;
    asm("v_cvt_pk_bf16_f32 %0, %1, %2" : "=v"(r) : "v"(a), "v"(b));
    return r;
}
static __device__ __forceinline__ void lds_fence() {
    asm volatile("s_waitcnt lgkmcnt(0)" ::: "memory");
}
#define MFMA16(a,b,c) __builtin_amdgcn_mfma_f32_16x16x32_bf16((a),(b),(c),0,0,0)

// byte offset into a [64][64]-bf16 row-major tile, XOR-swizzled (G4):
// row*128 + (col_bytes ^ ((row&7)<<4)); keeps 8B/16B alignment.
static __device__ __forceinline__ int lswz(int row, int col_shorts) {
    return row * 128 + ((col_shorts * 2) ^ ((row & 7) << 4));
}

__global__ __launch_bounds__(256, 4)
void dgn_kernel(const float* __restrict__ x, const float* __restrict__ emb,
                const float* __restrict__ w1, const float* __restrict__ b1,
                const float* __restrict__ w2, const float* __restrict__ b2,
                const float* __restrict__ w3, const float* __restrict__ b3,
                float* __restrict__ out, int n)
{
    __shared__ __align__(16) short lds_h[4][64][64];   // 32KB: h1/h2 (swizzled)
    __shared__ __align__(16) short lds_in[4][64][8];   //  4KB: in8 / out-staging

    const int tid  = threadIdx.x;
    const int wid  = tid >> 6;
    const int lane = tid & 63;
    const int cl   = lane & 15;
    const int kg   = lane >> 4;
    const int hb   = cl * 4;          // this lane's hid-slot base (col perm h = cl*4+nt)

    char  *LhB  = (char*)&lds_h[wid][0][0];
    short *Lin  = &lds_in[wid][0][0];
    float *Lo   = (float*)Lin;        // aliased output staging (Lin dead by layer 3)

    // ---------------- weight fragments (once per block) ----------------
    bf16x8 w1f[4];                    // B cols permuted: tile nt, col cl -> hid cl*4+nt
    #pragma unroll
    for (int nt = 0; nt < 4; ++nt) {
        bf16x8 f = {};
        if (kg == 0) {
            #pragma unroll
            for (int j = 0; j < 5; ++j) f[j] = (short)f2bf(w1[j * HID + hb + nt]);
        }
        w1f[nt] = f;
    }
    bf16x8 w2f[2][4];
    #pragma unroll
    for (int ks = 0; ks < 2; ++ks)
        #pragma unroll
        for (int nt = 0; nt < 4; ++nt) {
            bf16x8 f;
            #pragma unroll
            for (int j = 0; j < 8; ++j)
                f[j] = (short)f2bf(w2[(ks * 32 + kg * 8 + j) * HID + hb + nt]);
            w2f[ks][nt] = f;
        }
    bf16x8 w3f[2];                    // layer3 plain cols (cl<3)
    #pragma unroll
    for (int ks = 0; ks < 2; ++ks) {
        bf16x8 f = {};
        if (cl < 3) {
            #pragma unroll
            for (int j = 0; j < 8; ++j)
                f[j] = (short)f2bf(w3[(ks * 32 + kg * 8 + j) * 3 + cl]);
        }
        w3f[ks] = f;
    }
    float b1v[4], b2v[4];
    #pragma unroll
    for (int nt = 0; nt < 4; ++nt) { b1v[nt] = b1[hb + nt]; b2v[nt] = b2[hb + nt]; }
    const float b3v = (cl < 3) ? b3[cl] : 0.0f;

    const f32x4* __restrict__ emb4 = (const f32x4*)emb;

    // ---------------- main loop: 64 points / wave / iteration ----------------
    for (int base = blockIdx.x * 256; base < n; base += gridDim.x * 256) {
        const int wbase = base + wid * 64;
        const int pt    = wbase + lane;

        float idf = 0.f, u = 0.f, vv = 0.f;
        if (pt < n) {
            const float* xp = x + 3 * pt;
            idf = xp[0]; u = xp[1]; vv = xp[2];
        }
        int x0  = (int)(u * 1024.f); if (x0 == 1024) x0 = 0;
        int x1i = (x0 + 1 == 1024) ? 1023 : x0 + 1;
        int y0  = (int)(vv * 1024.f);
        int y1  = (y0 + 1 == 1024) ? 1023 : y0 + 1;
        float wx = u  * 1024.f - (float)x0;
        float wy = vv * 1024.f - (float)y0;

        f32x4 v00 = emb4[y0 * 1024 + x0];
        f32x4 v10 = emb4[y0 * 1024 + x1i];
        f32x4 v01 = emb4[y1 * 1024 + x0];
        f32x4 v11 = emb4[y1 * 1024 + x1i];
        f32x4 vup = v00 + (v10 - v00) * wx;
        f32x4 vdn = v01 + (v11 - v01) * wx;
        f32x4 g   = vup + (vdn - vup) * wy;

        // pack in8 = [idf, g0..g3, 0, 0, 0] bf16 -> LDS (bias now in acc-init)
        u32x4 inq = {cvt_pk_bf16(idf, g[0]), cvt_pk_bf16(g[1], g[2]),
                     cvt_pk_bf16(g[3], 0.f), 0u};
        *(u32x4*)(Lin + lane * 8) = inq;
        lds_fence();

        // -------- layer 1: K=32 (k>=5 zero), per-mt to cap registers --------
        #pragma unroll
        for (int mt = 0; mt < 4; ++mt) {
            bf16x8 af = {};
            if (kg == 0) af = *(const bf16x8*)(Lin + (mt * 16 + cl) * 8);
            f32x4 acc[4];
            #pragma unroll
            for (int nt = 0; nt < 4; ++nt) {
                acc[nt] = (f32x4){b1v[nt], b1v[nt], b1v[nt], b1v[nt]};
                acc[nt] = MFMA16(af, w1f[nt], acc[nt]);
            }
            #pragma unroll
            for (int r = 0; r < 4; ++r) {
                int row = mt * 16 + kg * 4 + r;
                u32x2 p = {cvt_pk_bf16(fmaxf(acc[0][r], 0.f), fmaxf(acc[1][r], 0.f)),
                           cvt_pk_bf16(fmaxf(acc[2][r], 0.f), fmaxf(acc[3][r], 0.f))};
                *(u32x2*)(LhB + lswz(row, hb)) = p;
            }
        }
        lds_fence();

        // -------- layer 2: K=64 --------
        #pragma unroll
        for (int mt = 0; mt < 4; ++mt) {
            int arow = mt * 16 + cl;
            bf16x8 a0 = *(const bf16x8*)(LhB + lswz(arow, kg * 8));
            bf16x8 a1 = *(const bf16x8*)(LhB + lswz(arow, 32 + kg * 8));
            f32x4 acc[4];
            #pragma unroll
            for (int nt = 0; nt < 4; ++nt) {
                acc[nt] = (f32x4){b2v[nt], b2v[nt], b2v[nt], b2v[nt]};
                acc[nt] = MFMA16(a0, w2f[0][nt], acc[nt]);
                acc[nt] = MFMA16(a1, w2f[1][nt], acc[nt]);
            }
            #pragma unroll
            for (int r = 0; r < 4; ++r) {
                int row = mt * 16 + kg * 4 + r;
                u32x2 p = {cvt_pk_bf16(fmaxf(acc[0][r], 0.f), fmaxf(acc[1][r], 0.f)),
                           cvt_pk_bf16(fmaxf(acc[2][r], 0.f), fmaxf(acc[3][r], 0.f))};
                *(u32x2*)(LhB + lswz(row, hb)) = p;
            }
        }
        lds_fence();

        // -------- layer 3: K=64, 3 cols (padded to 16) --------
        #pragma unroll
        for (int mt = 0; mt < 4; ++mt) {
            int arow = mt * 16 + cl;
            bf16x8 a0 = *(const bf16x8*)(LhB + lswz(arow, kg * 8));
            bf16x8 a1 = *(const bf16x8*)(LhB + lswz(arow, 32 + kg * 8));
            f32x4 acc = (f32x4){b3v, b3v, b3v, b3v};
            acc = MFMA16(a0, w3f[0], acc);
            acc = MFMA16(a1, w3f[1], acc);
            if (cl < 3) {
                #pragma unroll
                for (int r = 0; r < 4; ++r) {
                    float t = acc[r];
                    float s = 1.0f / (1.0f + __expf(-t));
                    Lo[(mt * 16 + kg * 4 + r) * 3 + cl] = s;
                }
            }
        }
        lds_fence();

        // coalesced output: 48 lanes store 16B each (192 floats = 64 pts x 3)
        if (wbase + 64 <= n) {
            if (lane < 48) {
                f32x4 o = *(const f32x4*)(Lo + lane * 4);
                *(f32x4*)(out + wbase * 3 + lane * 4) = o;
            }
        } else if (pt < n) {
            out[pt * 3 + 0] = Lo[lane * 3 + 0];
            out[pt * 3 + 1] = Lo[lane * 3 + 1];
            out[pt * 3 + 2] = Lo[lane * 3 + 2];
        }
    }
}

extern "C" void kernel_launch(void* const* d_in, const int* in_sizes, int n_in,
                              void* d_out, int out_size, void* d_ws, size_t ws_size,
                              hipStream_t stream) {
    const float* x   = (const float*)d_in[0];
    const float* emb = (const float*)d_in[1];
    const float* w1  = (const float*)d_in[2];
    const float* b1  = (const float*)d_in[3];
    const float* w2  = (const float*)d_in[4];
    const float* b2  = (const float*)d_in[5];
    const float* w3  = (const float*)d_in[6];
    const float* b3  = (const float*)d_in[7];
    float* out = (float*)d_out;

    int n = in_sizes[0] / 3;
    int nblk = (n + 255) / 256;
    if (nblk > 2048) nblk = 2048;
    dgn_kernel<<<dim3(nblk), dim3(256), 0, stream>>>(x, emb, w1, b1, w2, b2, w3, b3, out, n);
}

// Round 3
// 101.303 us; speedup vs baseline: 1.5477x; 1.5477x over previous
//
#include <hip/hip_runtime.h>
#include <hip/hip_bf16.h>

// DenseGridNet: bilinear gather + MLP(5->64->64->3) + sigmoid, bf16 MFMA.
// R3: bf16 emb table in d_ws (half gather bytes, 8MB L2-resident),
//     depth-2 software pipeline (issue next gathers before current MLP),
//     launch_bounds(256,3) to avoid R2's scratch-spill disaster.

typedef __attribute__((ext_vector_type(8))) short bf16x8;
typedef __attribute__((ext_vector_type(4))) float f32x4;
typedef __attribute__((ext_vector_type(2))) unsigned int u32x2;
typedef __attribute__((ext_vector_type(4))) unsigned int u32x4;
typedef unsigned long long u64t;

#define HID 64

static __device__ __forceinline__ unsigned short f2bf(float f) {
    __hip_bfloat16 h = __float2bfloat16(f);
    return __builtin_bit_cast(unsigned short, h);
}
static __device__ __forceinline__ unsigned cvt_pk_bf16(float a, float b) {
    unsigned r;
    asm("v_cvt_pk_bf16_f32 %0, %1, %2" : "=v"(r) : "v"(a), "v"(b));
    return r;
}
static __device__ __forceinline__ void lds_fence() {
    asm volatile("s_waitcnt lgkmcnt(0)" ::: "memory");
}
#define MFMA16(a,b,c) __builtin_amdgcn_mfma_f32_16x16x32_bf16((a),(b),(c),0,0,0)

// byte offset into [64][64]-bf16 tile, XOR-swizzled (conflict-free, measured 0)
static __device__ __forceinline__ int lswz(int row, int col_shorts) {
    return row * 128 + ((col_shorts * 2) ^ ((row & 7) << 4));
}
// unpack 4 packed bf16 (one texel) -> f32x4
static __device__ __forceinline__ f32x4 unpk(u64t q) {
    unsigned lo = (unsigned)q, hi = (unsigned)(q >> 32);
    f32x4 r;
    r[0] = __builtin_bit_cast(float, lo << 16);
    r[1] = __builtin_bit_cast(float, lo & 0xFFFF0000u);
    r[2] = __builtin_bit_cast(float, hi << 16);
    r[3] = __builtin_bit_cast(float, hi & 0xFFFF0000u);
    return r;
}

// fp32 emb (1M texels x 16B) -> bf16 table (1M x 8B) in workspace
__global__ __launch_bounds__(256) void conv_emb(const f32x4* __restrict__ emb,
                                                u32x2* __restrict__ tab) {
    int t = blockIdx.x * 256 + threadIdx.x;   // grid 4096 x 256 == 1M exactly
    f32x4 v = emb[t];
    u32x2 p = {cvt_pk_bf16(v[0], v[1]), cvt_pk_bf16(v[2], v[3])};
    tab[t] = p;
}

template<int BT>
__global__ __launch_bounds__(256, 3)
void dgn_kernel(const float* __restrict__ x, const void* __restrict__ tabv,
                const float* __restrict__ w1, const float* __restrict__ b1,
                const float* __restrict__ w2, const float* __restrict__ b2,
                const float* __restrict__ w3, const float* __restrict__ b3,
                float* __restrict__ out, int n)
{
    __shared__ __align__(16) short lds_h[4][64][64];   // 32KB (swizzled h1/h2)
    __shared__ __align__(16) short lds_in[4][64][8];   //  4KB in8 / out staging

    const int tid  = threadIdx.x;
    const int wid  = tid >> 6;
    const int lane = tid & 63;
    const int cl   = lane & 15;
    const int kg   = lane >> 4;
    const int hb   = cl * 4;          // col-permuted hid base: h = cl*4 + nt

    char  *LhB = (char*)&lds_h[wid][0][0];
    short *Lin = &lds_in[wid][0][0];
    float *Lo  = (float*)Lin;         // aliased out-staging (Lin dead by layer 3)

    // ---------------- weight fragments (once per block) ----------------
    bf16x8 w1f[4];
    #pragma unroll
    for (int nt = 0; nt < 4; ++nt) {
        bf16x8 f = {};
        if (kg == 0) {
            #pragma unroll
            for (int j = 0; j < 5; ++j) f[j] = (short)f2bf(w1[j * HID + hb + nt]);
        }
        w1f[nt] = f;
    }
    bf16x8 w2f[2][4];
    #pragma unroll
    for (int ks = 0; ks < 2; ++ks)
        #pragma unroll
        for (int nt = 0; nt < 4; ++nt) {
            bf16x8 f;
            #pragma unroll
            for (int j = 0; j < 8; ++j)
                f[j] = (short)f2bf(w2[(ks * 32 + kg * 8 + j) * HID + hb + nt]);
            w2f[ks][nt] = f;
        }
    bf16x8 w3f[2];
    #pragma unroll
    for (int ks = 0; ks < 2; ++ks) {
        bf16x8 f = {};
        if (cl < 3) {
            #pragma unroll
            for (int j = 0; j < 8; ++j)
                f[j] = (short)f2bf(w3[(ks * 32 + kg * 8 + j) * 3 + cl]);
        }
        w3f[ks] = f;
    }
    float b1v[4], b2v[4];
    #pragma unroll
    for (int nt = 0; nt < 4; ++nt) { b1v[nt] = b1[hb + nt]; b2v[nt] = b2[hb + nt]; }
    const float b3v = (cl < 3) ? b3[cl] : 0.0f;

    const u64t*  __restrict__ tab8 = (const u64t*)tabv;
    const f32x4* __restrict__ tabf = (const f32x4*)tabv;

    const int step = gridDim.x * 256;
    const int blk0 = blockIdx.x * 256;
    if (blk0 >= n) return;
    const int iters = (n - blk0 + step - 1) / step;
    const int wb0   = blk0 + wid * 64;

    // x-load: value assignment; issue point controlled by call site
    #define LOADX(I, A, B, C) { int pt_ = wb0 + (I) * step + lane;              \
        int pc_ = pt_ < n ? pt_ : 0; const float* xp_ = x + 3 * pc_;            \
        A = xp_[0]; B = xp_[1]; C = xp_[2]; }

    // compute indices/weights (exact reference semantics) and issue gathers
    #define GISSUE(U, V, Ga, Gb, Gc, Gd, Aa, Ab, Ac, Ad, WX, WY) {              \
        float uf_ = (U) * 1024.f, vf_ = (V) * 1024.f;                           \
        int x0_ = (int)uf_; if (x0_ == 1024) x0_ = 0;                           \
        int x1_ = (x0_ + 1 == 1024) ? 1023 : x0_ + 1;                           \
        int y0_ = (int)vf_;                                                     \
        WX = uf_ - (float)x0_; WY = vf_ - (float)y0_;                           \
        if (y0_ > 1023) y0_ = 1023;                                             \
        int y1_ = (y0_ + 1 > 1023) ? 1023 : y0_ + 1;                            \
        int r0_ = y0_ << 10, r1_ = y1_ << 10;                                   \
        if (BT) { Ga = tab8[r0_ + x0_]; Gb = tab8[r0_ + x1_];                   \
                  Gc = tab8[r1_ + x0_]; Gd = tab8[r1_ + x1_]; }                 \
        else    { Aa = r0_ + x0_; Ab = r0_ + x1_;                               \
                  Ac = r1_ + x0_; Ad = r1_ + x1_; } }

    // ---------------- pipeline prologue ----------------
    u64t g00 = 0, g10 = 0, g01 = 0, g11 = 0;
    int  a00 = 0, a10 = 0, a01 = 0, a11 = 0;
    float cwx, cwy, cid;
    float nxi, nxu, nxv;
    {
        float pxi, pxu, pxv;
        LOADX(0, pxi, pxu, pxv);
        GISSUE(pxu, pxv, g00, g10, g01, g11, a00, a10, a01, a11, cwx, cwy);
        cid = pxi;
        LOADX(1, nxi, nxu, nxv);
    }

    for (int i = 0; i < iters; ++i) {
        // issue set(i+1) gathers + set(i+2) x-load BEFORE this set's MLP
        u64t h00 = 0, h10 = 0, h01 = 0, h11 = 0;
        int  c00 = 0, c10 = 0, c01 = 0, c11 = 0;
        float hwx = 0.f, hwy = 0.f, hid = 0.f;
        const bool more = (i + 1 < iters);
        if (more) {
            GISSUE(nxu, nxv, h00, h10, h01, h11, c00, c10, c01, c11, hwx, hwy);
            hid = nxi;
            int nix = (i + 2 < iters) ? i + 2 : i + 1;
            LOADX(nix, nxi, nxu, nxv);
        }

        // ---------------- MLP for set i ----------------
        f32x4 v00, v10, v01, v11;
        if (BT) { v00 = unpk(g00); v10 = unpk(g10); v01 = unpk(g01); v11 = unpk(g11); }
        else    { v00 = tabf[a00]; v10 = tabf[a10]; v01 = tabf[a01]; v11 = tabf[a11]; }
        f32x4 vup = v00 + (v10 - v00) * cwx;
        f32x4 vdn = v01 + (v11 - v01) * cwx;
        f32x4 g   = vup + (vdn - vup) * cwy;

        u32x4 inq = {cvt_pk_bf16(cid, g[0]), cvt_pk_bf16(g[1], g[2]),
                     cvt_pk_bf16(g[3], 0.f), 0u};
        *(u32x4*)(Lin + lane * 8) = inq;
        lds_fence();

        // -------- layer 1: K=32 (k>=5 zero) --------
        #pragma unroll
        for (int mt = 0; mt < 4; ++mt) {
            bf16x8 af = {};
            if (kg == 0) af = *(const bf16x8*)(Lin + (mt * 16 + cl) * 8);
            f32x4 acc[4];
            #pragma unroll
            for (int nt = 0; nt < 4; ++nt) {
                acc[nt] = (f32x4){b1v[nt], b1v[nt], b1v[nt], b1v[nt]};
                acc[nt] = MFMA16(af, w1f[nt], acc[nt]);
            }
            #pragma unroll
            for (int r = 0; r < 4; ++r) {
                int row = mt * 16 + kg * 4 + r;
                u32x2 p = {cvt_pk_bf16(fmaxf(acc[0][r], 0.f), fmaxf(acc[1][r], 0.f)),
                           cvt_pk_bf16(fmaxf(acc[2][r], 0.f), fmaxf(acc[3][r], 0.f))};
                *(u32x2*)(LhB + lswz(row, hb)) = p;
            }
        }
        lds_fence();

        // -------- layer 2: K=64 --------
        #pragma unroll
        for (int mt = 0; mt < 4; ++mt) {
            int arow = mt * 16 + cl;
            bf16x8 a0 = *(const bf16x8*)(LhB + lswz(arow, kg * 8));
            bf16x8 a1 = *(const bf16x8*)(LhB + lswz(arow, 32 + kg * 8));
            f32x4 acc[4];
            #pragma unroll
            for (int nt = 0; nt < 4; ++nt) {
                acc[nt] = (f32x4){b2v[nt], b2v[nt], b2v[nt], b2v[nt]};
                acc[nt] = MFMA16(a0, w2f[0][nt], acc[nt]);
                acc[nt] = MFMA16(a1, w2f[1][nt], acc[nt]);
            }
            #pragma unroll
            for (int r = 0; r < 4; ++r) {
                int row = mt * 16 + kg * 4 + r;
                u32x2 p = {cvt_pk_bf16(fmaxf(acc[0][r], 0.f), fmaxf(acc[1][r], 0.f)),
                           cvt_pk_bf16(fmaxf(acc[2][r], 0.f), fmaxf(acc[3][r], 0.f))};
                *(u32x2*)(LhB + lswz(row, hb)) = p;
            }
        }
        lds_fence();

        // -------- layer 3: K=64, 3 cols --------
        #pragma unroll
        for (int mt = 0; mt < 4; ++mt) {
            int arow = mt * 16 + cl;
            bf16x8 a0 = *(const bf16x8*)(LhB + lswz(arow, kg * 8));
            bf16x8 a1 = *(const bf16x8*)(LhB + lswz(arow, 32 + kg * 8));
            f32x4 acc = (f32x4){b3v, b3v, b3v, b3v};
            acc = MFMA16(a0, w3f[0], acc);
            acc = MFMA16(a1, w3f[1], acc);
            if (cl < 3) {
                #pragma unroll
                for (int r = 0; r < 4; ++r) {
                    float t = acc[r];
                    float s = __builtin_amdgcn_rcpf(1.0f + __expf(-t));
                    Lo[(mt * 16 + kg * 4 + r) * 3 + cl] = s;
                }
            }
        }
        lds_fence();

        const int wbase = wb0 + i * step;
        if (wbase + 64 <= n) {
            if (lane < 48)
                *(f32x4*)(out + wbase * 3 + lane * 4) = *(const f32x4*)(Lo + lane * 4);
        } else {
            int pt = wbase + lane;
            if (pt < n) {
                out[pt * 3 + 0] = Lo[lane * 3 + 0];
                out[pt * 3 + 1] = Lo[lane * 3 + 1];
                out[pt * 3 + 2] = Lo[lane * 3 + 2];
            }
        }

        if (more) {
            g00 = h00; g10 = h10; g01 = h01; g11 = h11;
            a00 = c00; a10 = c10; a01 = c01; a11 = c11;
            cwx = hwx; cwy = hwy; cid = hid;
        }
    }
    #undef LOADX
    #undef GISSUE
}

extern "C" void kernel_launch(void* const* d_in, const int* in_sizes, int n_in,
                              void* d_out, int out_size, void* d_ws, size_t ws_size,
                              hipStream_t stream) {
    const float* x   = (const float*)d_in[0];
    const float* emb = (const float*)d_in[1];
    const float* w1  = (const float*)d_in[2];
    const float* b1  = (const float*)d_in[3];
    const float* w2  = (const float*)d_in[4];
    const float* b2  = (const float*)d_in[5];
    const float* w3  = (const float*)d_in[6];
    const float* b3  = (const float*)d_in[7];
    float* out = (float*)d_out;

    int n = in_sizes[0] / 3;
    int nblk = (n + 255) / 256;
    if (nblk > 2048) nblk = 2048;

    const size_t tab_bytes = (size_t)1024 * 1024 * 8;
    if (ws_size >= tab_bytes) {
        conv_emb<<<dim3(4096), dim3(256), 0, stream>>>((const f32x4*)emb, (u32x2*)d_ws);
        dgn_kernel<1><<<dim3(nblk), dim3(256), 0, stream>>>(
            x, d_ws, w1, b1, w2, b2, w3, b3, out, n);
    } else {
        dgn_kernel<0><<<dim3(nblk), dim3(256), 0, stream>>>(
            x, emb, w1, b1, w2, b2, w3, b3, out, n);
    }
}